// Round 1
// baseline (692.079 us; speedup 1.0000x reference)
//
#include <hip/hip_runtime.h>
#include <math.h>

// Problem constants
#define NB 128     // batch
#define NR 1152    // routes
#define NI 16      // in_ch
#define NO 32      // out_ch
#define NC 10      // capsules
#define RB 16      // routes per chunk
#define NCH (NR / RB)   // 72 chunks
#define BT 16      // batch tile

// Workspace layout (float offsets)
#define OFF_LOGITS 0
#define OFF_PART_S (OFF_LOGITS + NC*NB*NR)            // 1,474,560
#define OFF_PART_M (OFF_PART_S + NC*NCH*NB*NO)        // +2,949,120
#define OFF_PART_Z (OFF_PART_M + NC*NCH*NB)           // +92,160
#define OFF_OUTBUF (OFF_PART_Z + NC*NCH*NB)           // +92,160  (outbuf 40,960)

// MODE 0: uniform weights (iter 0), no logit update
// MODE 1: logits = pred . out_prev (write logits), online softmax
// MODE 2: logits += pred . out_prev (read logits, no write), online softmax
template<int MODE>
__global__ __launch_bounds__(256)
void pass_k(const float* __restrict__ x, const float* __restrict__ W,
            const float* __restrict__ out_prev, float* __restrict__ logits,
            float* __restrict__ part_s, float* __restrict__ part_M, float* __restrict__ part_Z)
{
    const int ch = blockIdx.x;
    const int c  = blockIdx.y;
    const int r0 = ch * RB;
    const int t  = threadIdx.x;

    // wlds: [r][o*20 + i]  (pad 20 to spread banks, keep 16B alignment)
    __shared__ __align__(16) float wlds[RB * 640];
    // xlds: [b][r*20 + i], per-b stride 324 (== 4 mod 32 for staged-write spread)
    __shared__ __align__(16) float xlds[BT * 324];
    __shared__ float olds[BT * NO];

    // ---- stage W chunk: 8192 contiguous floats, transpose to [r][o][i] ----
    {
        const float4* wg = (const float4*)(W + ((size_t)c * NR + r0) * (NI * NO));
        #pragma unroll
        for (int q = t; q < RB * NI * NO / 4; q += 256) {
            float4 v = wg[q];
            int r   = q >> 7;           // 128 float4 per r
            int rem = q & 127;          // float idx = 4*rem = i*32 + o
            int i   = rem >> 3;
            int o4  = (rem & 7) << 2;
            float* dst = &wlds[r * 640 + i];
            dst[(o4 + 0) * 20] = v.x;
            dst[(o4 + 1) * 20] = v.y;
            dst[(o4 + 2) * 20] = v.z;
            dst[(o4 + 3) * 20] = v.w;
        }
    }

    const int o  = t & 31;
    const int bq = t >> 5;   // 0..7

    for (int bt = 0; bt < NB / BT; ++bt) {
        const int b0 = bt * BT;
        __syncthreads();   // covers wlds staging (bt=0) and xlds reuse (bt>0)

        // ---- stage x tile: BT rows of 256 contiguous floats ----
        {
            int b_l = t >> 4, j0 = t & 15;
            const float4* xg = (const float4*)(x + (size_t)(b0 + b_l) * (NR * NI) + (size_t)r0 * NI);
            float* xdst = &xlds[b_l * 324];
            #pragma unroll
            for (int j = j0; j < RB * NI / 4; j += 16) {
                float4 v = xg[j];
                int r = j >> 2, i4 = (j & 3) << 2;
                *((float4*)&xdst[r * 20 + i4]) = v;
            }
        }
        if (MODE >= 1) {
            for (int q = t; q < BT * NO; q += 256) {
                int b_l = q >> 5, oo = q & 31;
                olds[q] = out_prev[((size_t)c * NB + b0 + b_l) * NO + oo];
            }
        }
        __syncthreads();

        float acc[2], Mr[2], Zr[2];
        #pragma unroll
        for (int bs = 0; bs < 2; ++bs) { acc[bs] = 0.f; Mr[bs] = -INFINITY; Zr[bs] = 0.f; }

        for (int r = 0; r < RB; ++r) {
            const float* wp = &wlds[r * 640 + o * 20];
            float4 w0 = *(const float4*)(wp + 0);
            float4 w1 = *(const float4*)(wp + 4);
            float4 w2 = *(const float4*)(wp + 8);
            float4 w3 = *(const float4*)(wp + 12);
            #pragma unroll
            for (int bs = 0; bs < 2; ++bs) {
                int b_l = bq + bs * 8;
                const float* xp = &xlds[b_l * 324 + r * 20];
                float4 x0 = *(const float4*)(xp + 0);
                float4 x1 = *(const float4*)(xp + 4);
                float4 x2 = *(const float4*)(xp + 8);
                float4 x3 = *(const float4*)(xp + 12);
                float p = x0.x*w0.x + x0.y*w0.y + x0.z*w0.z + x0.w*w0.w
                        + x1.x*w1.x + x1.y*w1.y + x1.z*w1.z + x1.w*w1.w
                        + x2.x*w2.x + x2.y*w2.y + x2.z*w2.z + x2.w*w2.w
                        + x3.x*w3.x + x3.y*w3.y + x3.z*w3.z + x3.w*w3.w;
                if (MODE == 0) {
                    acc[bs] += p;
                } else {
                    // logit dot: sum p*out over the 32 o-lanes of this group
                    float qv = p * olds[b_l * NO + o];
                    qv += __shfl_xor(qv, 1);
                    qv += __shfl_xor(qv, 2);
                    qv += __shfl_xor(qv, 4);
                    qv += __shfl_xor(qv, 8);
                    qv += __shfl_xor(qv, 16);
                    float lval = qv;
                    size_t lidx = ((size_t)c * NB + b0 + b_l) * NR + r0 + r;
                    if (MODE == 2) lval += logits[lidx];
                    if (MODE == 1) { if (o == 0) logits[lidx] = lval; }
                    // online softmax accumulate
                    float Mn  = fmaxf(Mr[bs], lval);
                    float sc  = __expf(Mr[bs] - Mn);   // exp(-inf)=0 first time
                    float wg_ = __expf(lval - Mn);
                    Zr[bs]  = Zr[bs] * sc + wg_;
                    acc[bs] = acc[bs] * sc + wg_ * p;
                    Mr[bs]  = Mn;
                }
            }
        }

        // ---- write chunk partials ----
        #pragma unroll
        for (int bs = 0; bs < 2; ++bs) {
            int b_l = bq + bs * 8;
            size_t pb = ((size_t)(c * NCH + ch) * NB + b0 + b_l);
            part_s[pb * NO + o] = acc[bs];
            if (MODE >= 1 && o == 0) { part_M[pb] = Mr[bs]; part_Z[pb] = Zr[bs]; }
        }
    }
}

// Merge chunk partials (log-sum-exp for softmax passes), squash across batch, write out.
template<int UNIFORM>
__global__ __launch_bounds__(256)
void reduce_squash_k(const float* __restrict__ part_s, const float* __restrict__ part_M,
                     const float* __restrict__ part_Z, float* __restrict__ outp)
{
    const int c = blockIdx.x;
    const int t = threadIdx.x;
    __shared__ float slds[NB * NO];     // 16 KB
    __shared__ float elds[NCH * NB];    // 36.9 KB
    __shared__ float rz[NB];
    __shared__ float red[8][NO];
    __shared__ float fo[NO];

    if (!UNIFORM) {
        if (t < NB) {
            float m = -INFINITY;
            for (int ch = 0; ch < NCH; ++ch)
                m = fmaxf(m, part_M[(size_t)(c * NCH + ch) * NB + t]);
            float z = 0.f;
            for (int ch = 0; ch < NCH; ++ch) {
                float e = __expf(part_M[(size_t)(c * NCH + ch) * NB + t] - m);
                elds[ch * NB + t] = e;
                z += part_Z[(size_t)(c * NCH + ch) * NB + t] * e;
            }
            rz[t] = 1.f / z;
        }
        __syncthreads();
    }

    const int o = t & 31, bq = t >> 5;
    for (int k = 0; k < 16; ++k) {
        int b = bq + 8 * k;
        float s = 0.f;
        for (int ch = 0; ch < NCH; ++ch) {
            float v = part_s[((size_t)(c * NCH + ch) * NB + b) * NO + o];
            s += UNIFORM ? v : v * elds[ch * NB + b];
        }
        s = UNIFORM ? (s * (1.0f / NR)) : (s * rz[b]);
        slds[b * NO + o] = s;
    }
    __syncthreads();

    float pn = 0.f;
    for (int k = 0; k < 16; ++k) { int b = bq + 8 * k; float v = slds[b * NO + o]; pn += v * v; }
    red[bq][o] = pn;
    __syncthreads();
    if (t < NO) {
        float n2 = 0.f;
        for (int j = 0; j < 8; ++j) n2 += red[j][t];
        fo[t] = sqrtf(n2) / (1.f + n2);   // (n2/(1+n2))/sqrt(n2)
    }
    __syncthreads();

    for (int k = 0; k < 16; ++k) {
        int b = bq + 8 * k;
        outp[((size_t)c * NB + b) * NO + o] = slds[b * NO + o] * fo[o];
    }
}

extern "C" void kernel_launch(void* const* d_in, const int* in_sizes, int n_in,
                              void* d_out, int out_size, void* d_ws, size_t ws_size,
                              hipStream_t stream)
{
    (void)in_sizes; (void)n_in; (void)out_size; (void)ws_size;
    const float* x = (const float*)d_in[0];
    const float* W = (const float*)d_in[1];
    float* ws     = (float*)d_ws;
    float* logits = ws + OFF_LOGITS;
    float* part_s = ws + OFF_PART_S;
    float* part_M = ws + OFF_PART_M;
    float* part_Z = ws + OFF_PART_Z;
    float* outbuf = ws + OFF_OUTBUF;
    float* outf   = (float*)d_out;

    dim3 g(NCH, NC), blk(256);

    // iter 0: uniform weights -> s0 -> squash -> out0
    pass_k<0><<<g, blk, 0, stream>>>(x, W, nullptr, nullptr, part_s, part_M, part_Z);
    reduce_squash_k<1><<<NC, blk, 0, stream>>>(part_s, part_M, part_Z, outbuf);
    // iter 1: logits = pred.out0 (store), online softmax, s1 -> out1
    pass_k<1><<<g, blk, 0, stream>>>(x, W, outbuf, logits, part_s, part_M, part_Z);
    reduce_squash_k<0><<<NC, blk, 0, stream>>>(part_s, part_M, part_Z, outbuf);
    // iter 2: logits += pred.out1 (no store), online softmax, s2 -> d_out
    pass_k<2><<<g, blk, 0, stream>>>(x, W, outbuf, logits, part_s, part_M, part_Z);
    reduce_squash_k<0><<<NC, blk, 0, stream>>>(part_s, part_M, part_Z, outf);
}

// Round 2
// 129.163 us; speedup vs baseline: 5.3582x; 5.3582x over previous
//
#include <hip/hip_runtime.h>
#include <math.h>

// Problem constants
#define NB 128     // batch
#define NR 1152    // routes
#define NI 16      // in_ch
#define NO 32      // out_ch
#define NC 10      // capsules

// ------------------------------------------------------------------
// NEW MFMA PATH
// ------------------------------------------------------------------
typedef __attribute__((ext_vector_type(8))) short bf16x8;
typedef __attribute__((ext_vector_type(4))) float f32x4;

__device__ __forceinline__ unsigned pk_bf16(float a, float b) {
    unsigned r;
    asm("v_cvt_pk_bf16_f32 %0, %1, %2" : "=v"(r) : "v"(a), "v"(b));
    return r;
}

// W[c][r][i][o] f32  ->  wts[((cr*2+hl)*32+o)*8 + iu] packed bf16 pairs
// hl=0: hi plane, hl=1: lo plane; each row = 16 bf16 (i=0..15) = 8 u32
__global__ __launch_bounds__(256) void convw_k(const float* __restrict__ W,
                                               unsigned* __restrict__ wts) {
    int tid = blockIdx.x * 256 + threadIdx.x;
    if (tid >= NC * NR * NO) return;
    int o = tid & 31;
    size_t cr = (size_t)(tid >> 5);
    const float* src = W + cr * (NI * NO) + o;
    float w[16], hf[16];
    unsigned hu[8], lu[8];
#pragma unroll
    for (int i = 0; i < 16; ++i) w[i] = src[(size_t)i * 32];
#pragma unroll
    for (int j = 0; j < 8; ++j) hu[j] = pk_bf16(w[2*j], w[2*j+1]);
#pragma unroll
    for (int j = 0; j < 8; ++j) {
        hf[2*j]   = __uint_as_float(hu[j] << 16);
        hf[2*j+1] = __uint_as_float(hu[j] & 0xffff0000u);
    }
#pragma unroll
    for (int j = 0; j < 8; ++j) lu[j] = pk_bf16(w[2*j] - hf[2*j], w[2*j+1] - hf[2*j+1]);
    unsigned* dh = wts + ((cr*2 + 0)*32 + o)*8;
    unsigned* dl = wts + ((cr*2 + 1)*32 + o)*8;
    ((uint4*)dh)[0] = make_uint4(hu[0], hu[1], hu[2], hu[3]);
    ((uint4*)dh)[1] = make_uint4(hu[4], hu[5], hu[6], hu[7]);
    ((uint4*)dl)[0] = make_uint4(lu[0], lu[1], lu[2], lu[3]);
    ((uint4*)dl)[1] = make_uint4(lu[4], lu[5], lu[6], lu[7]);
}

// pred[cc][b][r][o] f32 via bf16x3 MFMA; also per-chunk partial sums for iter0.
// grid (64 chunks of 18 routes, nb capsules), 256 thr = 4 waves, wave w owns b in [32w,32w+32)
__global__ __launch_bounds__(256) void predA_k(const float* __restrict__ x,
                                               const unsigned* __restrict__ wts,
                                               float* __restrict__ pred,
                                               float* __restrict__ part, int cbase) {
    const int ch = blockIdx.x;
    const int cc = blockIdx.y;
    const int c  = cbase + cc;
    const int t  = threadIdx.x;
    const int l  = t & 63, w = t >> 6;
    const int g  = l >> 4, q = l & 15;
    const int b0 = w * 32;
    const bool hi_lane = (g < 2);

    f32x4 sacc[2][2];
#pragma unroll
    for (int bt = 0; bt < 2; ++bt)
#pragma unroll
        for (int oh = 0; oh < 2; ++oh) sacc[bt][oh] = (f32x4){0.f, 0.f, 0.f, 0.f};

    for (int rr = 0; rr < 18; ++rr) {
        const int r = ch * 18 + rr;
        const size_t crb = (size_t)c * NR + r;
        bf16x8 B1[2];
#pragma unroll
        for (int oh = 0; oh < 2; ++oh) {
            const uint4* bp = (const uint4*)(wts + ((crb*2 + (size_t)(g >> 1))*32 + oh*16 + q)*8 + (g & 1)*4);
            union { uint4 u; bf16x8 v; } uu; uu.u = *bp;
            B1[oh] = uu.v;
        }
#pragma unroll
        for (int bt = 0; bt < 2; ++bt) {
            const int b = b0 + bt*16 + q;
            const float4* xp = (const float4*)(x + ((size_t)b * NR + r) * 16 + (g & 1) * 8);
            float4 xa = xp[0], xb = xp[1];
            unsigned h0 = pk_bf16(xa.x, xa.y), h1 = pk_bf16(xa.z, xa.w),
                     h2 = pk_bf16(xb.x, xb.y), h3 = pk_bf16(xb.z, xb.w);
            unsigned l0, l1, l2, l3;
            {
                float e0 = xa.x - __uint_as_float(h0 << 16);
                float e1 = xa.y - __uint_as_float(h0 & 0xffff0000u);
                float e2 = xa.z - __uint_as_float(h1 << 16);
                float e3 = xa.w - __uint_as_float(h1 & 0xffff0000u);
                float e4 = xb.x - __uint_as_float(h2 << 16);
                float e5 = xb.y - __uint_as_float(h2 & 0xffff0000u);
                float e6 = xb.z - __uint_as_float(h3 << 16);
                float e7 = xb.w - __uint_as_float(h3 & 0xffff0000u);
                l0 = pk_bf16(e0, e1); l1 = pk_bf16(e2, e3);
                l2 = pk_bf16(e4, e5); l3 = pk_bf16(e6, e7);
            }
            if (!hi_lane) { l0 = 0u; l1 = 0u; l2 = 0u; l3 = 0u; }
            union { unsigned u[4]; bf16x8 v; } ua1, ua2;
            ua1.u[0] = h0; ua1.u[1] = h1; ua1.u[2] = h2; ua1.u[3] = h3;
            ua2.u[0] = l0; ua2.u[1] = l1; ua2.u[2] = l2; ua2.u[3] = l3;
#pragma unroll
            for (int oh = 0; oh < 2; ++oh) {
                f32x4 acc = (f32x4){0.f, 0.f, 0.f, 0.f};
                acc = __builtin_amdgcn_mfma_f32_16x16x32_bf16(ua1.v, B1[oh], acc, 0, 0, 0);
                acc = __builtin_amdgcn_mfma_f32_16x16x32_bf16(ua2.v, B1[oh], acc, 0, 0, 0);
                sacc[bt][oh] += acc;
                const int brow = b0 + bt*16 + g*4;
                float* dst = pred + (((size_t)cc * NB + brow) * NR + r) * 32 + oh*16 + q;
#pragma unroll
                for (int reg = 0; reg < 4; ++reg)
                    dst[(size_t)reg * ((size_t)NR * 32)] = acc[reg];
            }
        }
    }
#pragma unroll
    for (int bt = 0; bt < 2; ++bt)
#pragma unroll
        for (int oh = 0; oh < 2; ++oh)
#pragma unroll
            for (int reg = 0; reg < 4; ++reg) {
                const int brow = b0 + bt*16 + g*4 + reg;
                part[(((size_t)cc * 64 + ch) * NB + brow) * 32 + oh*16 + q] = sacc[bt][oh][reg];
            }
}

// merge 64 chunk partials -> s0 = mean over routes. grid (128 b, nb c)
__global__ __launch_bounds__(256) void mergeS0_k(const float* __restrict__ part,
                                                 float* __restrict__ sbuf, int cbase) {
    const int b = blockIdx.x, cc = blockIdx.y, c = cbase + cc;
    const int t = threadIdx.x, o = t & 31, j = t >> 5;
    float s = 0.f;
#pragma unroll
    for (int k = 0; k < 8; ++k) {
        int ch = j * 8 + k;
        s += part[(((size_t)cc * 64 + ch) * NB + b) * 32 + o];
    }
    __shared__ float red[8][33];
    red[j][o] = s;
    __syncthreads();
    if (t < 32) {
        float tot = 0.f;
#pragma unroll
        for (int k = 0; k < 8; ++k) tot += red[k][t];
        sbuf[((size_t)c * NB + b) * 32 + t] = tot * (1.0f / 1152.0f);
    }
}

// routing iteration: logit = pred . out_acc, softmax over r, s = weighted sum.
// grid (128 b, nb c); lane owns whole routes (no cross-lane ops in hot loop)
__global__ __launch_bounds__(256) void softB_k(const float* __restrict__ pred,
                                               const float* __restrict__ oacc,
                                               float* __restrict__ sbuf, int cbase) {
    const int b = blockIdx.x, cc = blockIdx.y, c = cbase + cc;
    const int t = threadIdx.x;
    const float* op = oacc + ((size_t)c * NB + b) * 32;
    float ov[32];
#pragma unroll
    for (int j = 0; j < 32; ++j)
        ov[j] = __uint_as_float(__builtin_amdgcn_readfirstlane(__float_as_uint(op[j])));

    float accs[32];
#pragma unroll
    for (int j = 0; j < 32; ++j) accs[j] = 0.f;
    float Z = 0.f;

    const float* pb = pred + ((size_t)cc * NB + b) * NR * 32;
    for (int r = t; r < NR; r += 256) {
        const float4* pr = (const float4*)(pb + (size_t)r * 32);
        float4 p[8];
#pragma unroll
        for (int k = 0; k < 8; ++k) p[k] = pr[k];
        float d0 = 0.f, d1 = 0.f, d2 = 0.f, d3 = 0.f;
#pragma unroll
        for (int k = 0; k < 8; ++k) {
            d0 = fmaf(p[k].x, ov[4*k+0], d0);
            d1 = fmaf(p[k].y, ov[4*k+1], d1);
            d2 = fmaf(p[k].z, ov[4*k+2], d2);
            d3 = fmaf(p[k].w, ov[4*k+3], d3);
        }
        float e = __expf(((d0 + d1) + (d2 + d3)) - 20.0f);
        Z += e;
#pragma unroll
        for (int k = 0; k < 8; ++k) {
            accs[4*k+0] = fmaf(e, p[k].x, accs[4*k+0]);
            accs[4*k+1] = fmaf(e, p[k].y, accs[4*k+1]);
            accs[4*k+2] = fmaf(e, p[k].z, accs[4*k+2]);
            accs[4*k+3] = fmaf(e, p[k].w, accs[4*k+3]);
        }
    }

    __shared__ float buf[256 * 35];
#pragma unroll
    for (int j = 0; j < 32; ++j) buf[t * 35 + j] = accs[j];
    buf[t * 35 + 32] = Z;
    __syncthreads();

    const int o = t & 31, grp = t >> 5;
    float ps = 0.f;
#pragma unroll
    for (int k = 0; k < 32; ++k) ps += buf[(grp * 32 + k) * 35 + o];
    float pz = 0.f;
    if (t < 8) {
#pragma unroll
        for (int k = 0; k < 32; ++k) pz += buf[(t * 32 + k) * 35 + 32];
    }
    __syncthreads();
    buf[grp * 35 + o] = ps;
    if (t < 8) buf[t * 35 + 32] = pz;
    __syncthreads();
    if (t < 32) {
        float s = 0.f, z = 0.f;
#pragma unroll
        for (int k = 0; k < 8; ++k) { s += buf[k * 35 + t]; z += buf[k * 35 + 32]; }
        sbuf[((size_t)c * NB + b) * 32 + t] = s / z;
    }
}

// squash across batch. MODE 0: oacc = out; 1: oacc += out; 2: d_out = out
template<int MODE>
__global__ __launch_bounds__(256) void squashC_k(const float* __restrict__ sbuf,
                                                 float* __restrict__ oacc,
                                                 float* __restrict__ outp, int cbase) {
    const int c = cbase + blockIdx.x;
    const int t = threadIdx.x, o = t & 31, bq = t >> 5;
    const float* sp = sbuf + (size_t)c * NB * 32;
    float sv[16];
    float pn = 0.f;
#pragma unroll
    for (int k = 0; k < 16; ++k) {
        sv[k] = sp[(size_t)(bq + 8 * k) * 32 + o];
        pn = fmaf(sv[k], sv[k], pn);
    }
    __shared__ float red[8][33];
    red[bq][o] = pn;
    __syncthreads();
    float n2 = 0.f;
#pragma unroll
    for (int j = 0; j < 8; ++j) n2 += red[j][o];
    float f = sqrtf(n2) / (1.0f + n2);
#pragma unroll
    for (int k = 0; k < 16; ++k) {
        int b = bq + 8 * k;
        float v = sv[k] * f;
        if (MODE == 0) oacc[((size_t)c * NB + b) * 32 + o] = v;
        if (MODE == 1) oacc[((size_t)c * NB + b) * 32 + o] += v;
        if (MODE == 2) outp[((size_t)c * NB + b) * 32 + o] = v;
    }
}

// ------------------------------------------------------------------
// LEGACY FALLBACK (round-1 kernels, used only if ws_size is small)
// ------------------------------------------------------------------
#define RB 16
#define NCH (NR / RB)
#define BT 16
#define OFF_LOGITS 0
#define OFF_PART_S (OFF_LOGITS + NC*NB*NR)
#define OFF_PART_M (OFF_PART_S + NC*NCH*NB*NO)
#define OFF_PART_Z (OFF_PART_M + NC*NCH*NB)
#define OFF_OUTBUF (OFF_PART_Z + NC*NCH*NB)

template<int MODE>
__global__ __launch_bounds__(256)
void pass_k(const float* __restrict__ x, const float* __restrict__ W,
            const float* __restrict__ out_prev, float* __restrict__ logits,
            float* __restrict__ part_s, float* __restrict__ part_M, float* __restrict__ part_Z)
{
    const int ch = blockIdx.x;
    const int c  = blockIdx.y;
    const int r0 = ch * RB;
    const int t  = threadIdx.x;
    __shared__ __align__(16) float wlds[RB * 640];
    __shared__ __align__(16) float xlds[BT * 324];
    __shared__ float olds[BT * NO];
    {
        const float4* wg = (const float4*)(W + ((size_t)c * NR + r0) * (NI * NO));
        #pragma unroll
        for (int qq = t; qq < RB * NI * NO / 4; qq += 256) {
            float4 v = wg[qq];
            int r = qq >> 7, rem = qq & 127, i = rem >> 3, o4 = (rem & 7) << 2;
            float* dst = &wlds[r * 640 + i];
            dst[(o4 + 0) * 20] = v.x; dst[(o4 + 1) * 20] = v.y;
            dst[(o4 + 2) * 20] = v.z; dst[(o4 + 3) * 20] = v.w;
        }
    }
    const int o  = t & 31;
    const int bq = t >> 5;
    for (int bt = 0; bt < NB / BT; ++bt) {
        const int b0 = bt * BT;
        __syncthreads();
        {
            int b_l = t >> 4, j0 = t & 15;
            const float4* xg = (const float4*)(x + (size_t)(b0 + b_l) * (NR * NI) + (size_t)r0 * NI);
            float* xdst = &xlds[b_l * 324];
            #pragma unroll
            for (int j = j0; j < RB * NI / 4; j += 16) {
                float4 v = xg[j];
                int r = j >> 2, i4 = (j & 3) << 2;
                *((float4*)&xdst[r * 20 + i4]) = v;
            }
        }
        if (MODE >= 1) {
            for (int qq = t; qq < BT * NO; qq += 256) {
                int b_l = qq >> 5, oo = qq & 31;
                olds[qq] = out_prev[((size_t)c * NB + b0 + b_l) * NO + oo];
            }
        }
        __syncthreads();
        float acc[2], Mr[2], Zr[2];
        #pragma unroll
        for (int bs = 0; bs < 2; ++bs) { acc[bs] = 0.f; Mr[bs] = -INFINITY; Zr[bs] = 0.f; }
        for (int r = 0; r < RB; ++r) {
            const float* wp = &wlds[r * 640 + o * 20];
            float4 w0 = *(const float4*)(wp + 0);
            float4 w1 = *(const float4*)(wp + 4);
            float4 w2 = *(const float4*)(wp + 8);
            float4 w3 = *(const float4*)(wp + 12);
            #pragma unroll
            for (int bs = 0; bs < 2; ++bs) {
                int b_l = bq + bs * 8;
                const float* xp = &xlds[b_l * 324 + r * 20];
                float4 x0 = *(const float4*)(xp + 0);
                float4 x1 = *(const float4*)(xp + 4);
                float4 x2 = *(const float4*)(xp + 8);
                float4 x3 = *(const float4*)(xp + 12);
                float p = x0.x*w0.x + x0.y*w0.y + x0.z*w0.z + x0.w*w0.w
                        + x1.x*w1.x + x1.y*w1.y + x1.z*w1.z + x1.w*w1.w
                        + x2.x*w2.x + x2.y*w2.y + x2.z*w2.z + x2.w*w2.w
                        + x3.x*w3.x + x3.y*w3.y + x3.z*w3.z + x3.w*w3.w;
                if (MODE == 0) {
                    acc[bs] += p;
                } else {
                    float qv = p * olds[b_l * NO + o];
                    qv += __shfl_xor(qv, 1);
                    qv += __shfl_xor(qv, 2);
                    qv += __shfl_xor(qv, 4);
                    qv += __shfl_xor(qv, 8);
                    qv += __shfl_xor(qv, 16);
                    float lval = qv;
                    size_t lidx = ((size_t)c * NB + b0 + b_l) * NR + r0 + r;
                    if (MODE == 2) lval += logits[lidx];
                    if (MODE == 1) { if (o == 0) logits[lidx] = lval; }
                    float Mn  = fmaxf(Mr[bs], lval);
                    float sc  = __expf(Mr[bs] - Mn);
                    float wg_ = __expf(lval - Mn);
                    Zr[bs]  = Zr[bs] * sc + wg_;
                    acc[bs] = acc[bs] * sc + wg_ * p;
                    Mr[bs]  = Mn;
                }
            }
        }
        #pragma unroll
        for (int bs = 0; bs < 2; ++bs) {
            int b_l = bq + bs * 8;
            size_t pb = ((size_t)(c * NCH + ch) * NB + b0 + b_l);
            part_s[pb * NO + o] = acc[bs];
            if (MODE >= 1 && o == 0) { part_M[pb] = Mr[bs]; part_Z[pb] = Zr[bs]; }
        }
    }
}

template<int UNIFORM>
__global__ __launch_bounds__(256)
void reduce_squash_k(const float* __restrict__ part_s, const float* __restrict__ part_M,
                     const float* __restrict__ part_Z, float* __restrict__ outp)
{
    const int c = blockIdx.x;
    const int t = threadIdx.x;
    __shared__ float slds[NB * NO];
    __shared__ float elds[NCH * NB];
    __shared__ float rz[NB];
    __shared__ float red[8][NO];
    __shared__ float fo[NO];
    if (!UNIFORM) {
        if (t < NB) {
            float m = -INFINITY;
            for (int ch = 0; ch < NCH; ++ch)
                m = fmaxf(m, part_M[(size_t)(c * NCH + ch) * NB + t]);
            float z = 0.f;
            for (int ch = 0; ch < NCH; ++ch) {
                float e = __expf(part_M[(size_t)(c * NCH + ch) * NB + t] - m);
                elds[ch * NB + t] = e;
                z += part_Z[(size_t)(c * NCH + ch) * NB + t] * e;
            }
            rz[t] = 1.f / z;
        }
        __syncthreads();
    }
    const int o = t & 31, bq = t >> 5;
    for (int k = 0; k < 16; ++k) {
        int b = bq + 8 * k;
        float s = 0.f;
        for (int ch = 0; ch < NCH; ++ch) {
            float v = part_s[((size_t)(c * NCH + ch) * NB + b) * NO + o];
            s += UNIFORM ? v : v * elds[ch * NB + b];
        }
        s = UNIFORM ? (s * (1.0f / NR)) : (s * rz[b]);
        slds[b * NO + o] = s;
    }
    __syncthreads();
    float pn = 0.f;
    for (int k = 0; k < 16; ++k) { int b = bq + 8 * k; float v = slds[b * NO + o]; pn += v * v; }
    red[bq][o] = pn;
    __syncthreads();
    if (t < NO) {
        float n2 = 0.f;
        for (int j = 0; j < 8; ++j) n2 += red[j][t];
        fo[t] = sqrtf(n2) / (1.f + n2);
    }
    __syncthreads();
    for (int k = 0; k < 16; ++k) {
        int b = bq + 8 * k;
        outp[((size_t)c * NB + b) * NO + o] = slds[b * NO + o] * fo[o];
    }
}

// ------------------------------------------------------------------
extern "C" void kernel_launch(void* const* d_in, const int* in_sizes, int n_in,
                              void* d_out, int out_size, void* d_ws, size_t ws_size,
                              hipStream_t stream)
{
    (void)in_sizes; (void)n_in; (void)out_size;
    const float* x = (const float*)d_in[0];
    const float* W = (const float*)d_in[1];
    float* wsf  = (float*)d_ws;
    float* outf = (float*)d_out;

    // new-path ws offsets (in floats)
    const size_t OFFS_SBUF = 5898240;        // after wts (10*1152*2*32*8 u32)
    const size_t OFFS_OACC = OFFS_SBUF + (size_t)NC*NB*32;
    const size_t OFFS_PART = OFFS_OACC + (size_t)NC*NB*32;
    const size_t PART_PER_C = 64 * NB * 32;      // 262144
    const size_t PRED_PER_C = (size_t)NB * NR * 32;  // 4718592

    int cb = 0;
    const int cand[4] = {10, 5, 2, 1};
    for (int i = 0; i < 4; ++i) {
        size_t need = (OFFS_PART + (size_t)cand[i] * (PART_PER_C + PRED_PER_C)) * 4;
        if (ws_size >= need) { cb = cand[i]; break; }
    }

    if (cb > 0) {
        unsigned* wts = (unsigned*)d_ws;
        float* sbuf = wsf + OFFS_SBUF;
        float* oacc = wsf + OFFS_OACC;
        float* part = wsf + OFFS_PART;
        float* pred = wsf + OFFS_PART + (size_t)cb * PART_PER_C;

        convw_k<<<1440, 256, 0, stream>>>(W, wts);
        for (int cbase = 0; cbase < NC; cbase += cb) {
            int nb = (NC - cbase < cb) ? (NC - cbase) : cb;
            predA_k<<<dim3(64, nb), 256, 0, stream>>>(x, wts, pred, part, cbase);
            mergeS0_k<<<dim3(NB, nb), 256, 0, stream>>>(part, sbuf, cbase);
            squashC_k<0><<<nb, 256, 0, stream>>>(sbuf, oacc, nullptr, cbase);
            softB_k<<<dim3(NB, nb), 256, 0, stream>>>(pred, oacc, sbuf, cbase);
            squashC_k<1><<<nb, 256, 0, stream>>>(sbuf, oacc, nullptr, cbase);
            softB_k<<<dim3(NB, nb), 256, 0, stream>>>(pred, oacc, sbuf, cbase);
            squashC_k<2><<<nb, 256, 0, stream>>>(sbuf, oacc, outf, cbase);
        }
    } else {
        float* logits = wsf + OFF_LOGITS;
        float* part_s = wsf + OFF_PART_S;
        float* part_M = wsf + OFF_PART_M;
        float* part_Z = wsf + OFF_PART_Z;
        float* outbuf = wsf + OFF_OUTBUF;
        dim3 g(NCH, NC), blk(256);
        pass_k<0><<<g, blk, 0, stream>>>(x, W, nullptr, nullptr, part_s, part_M, part_Z);
        reduce_squash_k<1><<<NC, blk, 0, stream>>>(part_s, part_M, part_Z, outbuf);
        pass_k<1><<<g, blk, 0, stream>>>(x, W, outbuf, logits, part_s, part_M, part_Z);
        reduce_squash_k<0><<<NC, blk, 0, stream>>>(part_s, part_M, part_Z, outbuf);
        pass_k<2><<<g, blk, 0, stream>>>(x, W, outbuf, logits, part_s, part_M, part_Z);
        reduce_squash_k<0><<<NC, blk, 0, stream>>>(part_s, part_M, part_Z, outf);
    }
}

// Round 3
// 106.694 us; speedup vs baseline: 6.4866x; 1.2106x over previous
//
#include <hip/hip_runtime.h>
#include <math.h>

// Problem constants
#define NB 128     // batch
#define NR 1152    // routes
#define NI 16      // in_ch
#define NO 32      // out_ch
#define NC 10      // capsules
#define NCHK 48    // softmax partial chunks per capsule (12 grid-chunks x 4 wave-subs)

typedef __attribute__((ext_vector_type(8))) short bf16x8;
typedef __attribute__((ext_vector_type(4))) float f32x4;

__device__ __forceinline__ unsigned pk_bf16(float a, float b) {
    unsigned r;
    asm("v_cvt_pk_bf16_f32 %0, %1, %2" : "=v"(r) : "v"(a), "v"(b));
    return r;
}

// ------------------------------------------------------------------
// convw: W[c][r][i][o] f32 -> wts[((cr*2+hl)*32+o)*8 + j] bf16-pair u32
// hl=0 hi plane, hl=1 lo plane (bf16x3 split). Row = 16 i-consecutive bf16.
// ------------------------------------------------------------------
__global__ __launch_bounds__(256) void convw_k(const float* __restrict__ W,
                                               unsigned* __restrict__ wts) {
    int tid = blockIdx.x * 256 + threadIdx.x;
    if (tid >= NC * NR * NO) return;
    int o = tid & 31;
    size_t cr = (size_t)(tid >> 5);
    const float* src = W + cr * (NI * NO) + o;
    float w[16], hf[16];
    unsigned hu[8], lu[8];
#pragma unroll
    for (int i = 0; i < 16; ++i) w[i] = src[(size_t)i * 32];
#pragma unroll
    for (int j = 0; j < 8; ++j) hu[j] = pk_bf16(w[2*j], w[2*j+1]);
#pragma unroll
    for (int j = 0; j < 8; ++j) {
        hf[2*j]   = __uint_as_float(hu[j] << 16);
        hf[2*j+1] = __uint_as_float(hu[j] & 0xffff0000u);
    }
#pragma unroll
    for (int j = 0; j < 8; ++j) lu[j] = pk_bf16(w[2*j] - hf[2*j], w[2*j+1] - hf[2*j+1]);
    unsigned* dh = wts + ((cr*2 + 0)*32 + o)*8;
    unsigned* dl = wts + ((cr*2 + 1)*32 + o)*8;
    ((uint4*)dh)[0] = make_uint4(hu[0], hu[1], hu[2], hu[3]);
    ((uint4*)dh)[1] = make_uint4(hu[4], hu[5], hu[6], hu[7]);
    ((uint4*)dl)[0] = make_uint4(lu[0], lu[1], lu[2], lu[3]);
    ((uint4*)dl)[1] = make_uint4(lu[4], lu[5], lu[6], lu[7]);
}

// ------------------------------------------------------------------
// convx: x[b][r][i] f32 -> xts[plane][(r*128+b)*8 + j] bf16-pair u32
// (r-major so pass_f x-loads are lane-coalesced over b)
// ------------------------------------------------------------------
__global__ __launch_bounds__(256) void convx_k(const float* __restrict__ x,
                                               unsigned* __restrict__ xts) {
    int tid = blockIdx.x * 256 + threadIdx.x;
    if (tid >= NR * NB) return;
    int r = tid >> 7, b = tid & 127;
    const float4* src = (const float4*)(x + ((size_t)b * NR + r) * 16);
    float4 a0 = src[0], a1 = src[1], a2 = src[2], a3 = src[3];
    float v[16] = {a0.x,a0.y,a0.z,a0.w, a1.x,a1.y,a1.z,a1.w,
                   a2.x,a2.y,a2.z,a2.w, a3.x,a3.y,a3.z,a3.w};
    unsigned hu[8], lu[8];
#pragma unroll
    for (int j = 0; j < 8; ++j) hu[j] = pk_bf16(v[2*j], v[2*j+1]);
#pragma unroll
    for (int j = 0; j < 8; ++j) {
        float h0 = __uint_as_float(hu[j] << 16);
        float h1 = __uint_as_float(hu[j] & 0xffff0000u);
        lu[j] = pk_bf16(v[2*j] - h0, v[2*j+1] - h1);
    }
    uint4* dh = (uint4*)(xts + (size_t)tid * 8);
    dh[0] = make_uint4(hu[0], hu[1], hu[2], hu[3]);
    dh[1] = make_uint4(hu[4], hu[5], hu[6], hu[7]);
    uint4* dl = (uint4*)(xts + (size_t)(NR * NB) * 8 + (size_t)tid * 8);
    dl[0] = make_uint4(lu[0], lu[1], lu[2], lu[3]);
    dl[1] = make_uint4(lu[4], lu[5], lu[6], lu[7]);
}

// ------------------------------------------------------------------
// pass_f: fused pred-recompute + (uniform | softmax-weighted) r-reduction.
// Transposed MFMA: A = W (M=o), B = x (N=batch). D: col(l&15)=batch,
// row(g*4+reg)=o -> each lane owns batch b0+q with 8 of 32 o-values.
// MODE 0: acc += pred (iter 0, uniform). MODE 1: logit = pred.oacc,
// e = exp(logit-20), Z += e, acc += e*pred (iters 1,2).
// Grid: 960 blocks (10 c x 8 bt x 12 rch), XCD-chunked swizzle.
// 4 waves/block: all share 16-batch tile, split 96 routes 4-ways (24 each).
// ------------------------------------------------------------------
template<int MODE>
__global__ __launch_bounds__(256) void pass_f(const unsigned* __restrict__ xts,
                                              const unsigned* __restrict__ wts,
                                              const float* __restrict__ oacc,
                                              float* __restrict__ part_s,
                                              float* __restrict__ pZ)
{
    // XCD-chunked logical index: 960 blocks, 120 per XCD, bt-inner for W sharing
    int p = blockIdx.x;
    int lin = (p & 7) * 120 + (p >> 3);
    int c = lin / 96;
    int rem = lin - c * 96;
    int rch = rem >> 3;          // 0..11
    int bt  = rem & 7;           // 0..7

    const int t = threadIdx.x, w = t >> 6, l = t & 63, g = l >> 4, q = l & 15;
    const int b0 = bt * 16;
    const int r0 = rch * 96 + w * 24;
    const int ich = rch * 4 + w;     // 0..47
    const int b = b0 + q;
    const bool glo = (g < 2);

    float4 ov0, ov1;
    if (MODE == 1) {
        const float* op = oacc + ((size_t)c * NB + b) * 32 + g * 4;
        ov0 = *(const float4*)(op);
        ov1 = *(const float4*)(op + 16);
    }
    f32x4 acc0 = {0.f,0.f,0.f,0.f}, acc1 = {0.f,0.f,0.f,0.f};
    float Z = 0.f;

    const unsigned* xh = xts + ((size_t)r0 * 128 + b) * 8 + (g & 1) * 4;
    const unsigned* xl = xh + (size_t)(NR * NB) * 8;
    const unsigned* wp = wts + (((size_t)(c * NR + r0) * 2 + (g >> 1)) * 32 + q) * 8 + (g & 1) * 4;

#pragma unroll 4
    for (int rr = 0; rr < 24; ++rr) {
        union { uint4 u; bf16x8 v; } Xh, Xl, A0, A1;
        Xh.u = *(const uint4*)(xh + (size_t)rr * 1024);
        Xl.u = glo ? *(const uint4*)(xl + (size_t)rr * 1024) : make_uint4(0,0,0,0);
        A0.u = *(const uint4*)(wp + (size_t)rr * 512);
        A1.u = *(const uint4*)(wp + (size_t)rr * 512 + 128);
        f32x4 p0 = {0.f,0.f,0.f,0.f}, p1 = {0.f,0.f,0.f,0.f};
        // A=[Wh||Wl] (plane by g>>1), B=[xh;xh] -> Wh.xh + Wl.xh
        p0 = __builtin_amdgcn_mfma_f32_16x16x32_bf16(A0.v, Xh.v, p0, 0, 0, 0);
        // A=[Wh||Wl], B=[xl;0] (g>=2 zeroed) -> Wh.xl
        p0 = __builtin_amdgcn_mfma_f32_16x16x32_bf16(A0.v, Xl.v, p0, 0, 0, 0);
        p1 = __builtin_amdgcn_mfma_f32_16x16x32_bf16(A1.v, Xh.v, p1, 0, 0, 0);
        p1 = __builtin_amdgcn_mfma_f32_16x16x32_bf16(A1.v, Xl.v, p1, 0, 0, 0);
        if (MODE == 0) {
            acc0 += p0; acc1 += p1;
        } else {
            float d = p0[0]*ov0.x + p0[1]*ov0.y + p0[2]*ov0.z + p0[3]*ov0.w
                    + p1[0]*ov1.x + p1[1]*ov1.y + p1[2]*ov1.z + p1[3]*ov1.w;
            d += __shfl_xor(d, 16);
            d += __shfl_xor(d, 32);
            float e = __expf(d - 20.0f);
            Z += e;
            acc0[0] = fmaf(e, p0[0], acc0[0]);
            acc0[1] = fmaf(e, p0[1], acc0[1]);
            acc0[2] = fmaf(e, p0[2], acc0[2]);
            acc0[3] = fmaf(e, p0[3], acc0[3]);
            acc1[0] = fmaf(e, p1[0], acc1[0]);
            acc1[1] = fmaf(e, p1[1], acc1[1]);
            acc1[2] = fmaf(e, p1[2], acc1[2]);
            acc1[3] = fmaf(e, p1[3], acc1[3]);
        }
    }

    size_t base = (((size_t)c * NCHK + ich) * NB + b) * 32 + g * 4;
    *(float4*)(part_s + base)      = make_float4(acc0[0], acc0[1], acc0[2], acc0[3]);
    *(float4*)(part_s + base + 16) = make_float4(acc1[0], acc1[1], acc1[2], acc1[3]);
    if (MODE == 1 && g == 0)
        pZ[((size_t)c * NCHK + ich) * NB + b] = Z;
}

// ------------------------------------------------------------------
// msq: merge chunk partials -> s, squash over batch, update oacc / out.
// MODE 0: uniform partials (s = sum/1152), oacc = squash(s)
// MODE 1: softmax partials (s = sum/Z),   oacc += squash(s)
// MODE 2: softmax partials,               d_out = squash(s)
// Grid (10 c, 4 o-groups), 256 thr: t = b_lo(32) x o_off(8)
// ------------------------------------------------------------------
template<int MODE>
__global__ __launch_bounds__(256) void msq_k(const float* __restrict__ part_s,
                                             const float* __restrict__ pZ,
                                             float* __restrict__ oacc,
                                             float* __restrict__ dout)
{
    const int c = blockIdx.x, og = blockIdx.y;
    const int t = threadIdx.x;
    const int o_off = t & 7, b_lo = t >> 3;
    const int o = og * 8 + o_off;

    float sv[4];
    float pn = 0.f;
#pragma unroll
    for (int k = 0; k < 4; ++k) {
        int bb = b_lo + 32 * k;
        float s = 0.f;
#pragma unroll
        for (int ch = 0; ch < NCHK; ++ch)
            s += part_s[(((size_t)c * NCHK + ch) * NB + bb) * 32 + o];
        if (MODE == 0) {
            sv[k] = s * (1.0f / 1152.0f);
        } else {
            float z = 0.f;
#pragma unroll
            for (int ch = 0; ch < NCHK; ++ch)
                z += pZ[((size_t)c * NCHK + ch) * NB + bb];
            sv[k] = s / z;
        }
        pn = fmaf(sv[k], sv[k], pn);
    }
    __shared__ float red[256];
    __shared__ float fsh[8];
    red[t] = pn;
    __syncthreads();
    if (t < 8) {
        float n2 = 0.f;
#pragma unroll
        for (int j = 0; j < 32; ++j) n2 += red[t + 8 * j];
        fsh[t] = sqrtf(n2) / (1.0f + n2);   // (n2/(1+n2))/sqrt(n2)
    }
    __syncthreads();
    float f = fsh[o_off];
#pragma unroll
    for (int k = 0; k < 4; ++k) {
        int bb = b_lo + 32 * k;
        float v = sv[k] * f;
        size_t idx = ((size_t)c * NB + bb) * 32 + o;
        if (MODE == 0) oacc[idx] = v;
        if (MODE == 1) oacc[idx] += v;
        if (MODE == 2) dout[idx] = v;
    }
}

// ------------------------------------------------------------------
// LEGACY FALLBACK (round-1 kernels, used only if ws_size is small)
// ------------------------------------------------------------------
#define RB 16
#define LNCH (NR / RB)
#define BT 16
#define OFF_LOGITS 0
#define OFF_PART_S (OFF_LOGITS + NC*NB*NR)
#define OFF_PART_M (OFF_PART_S + NC*LNCH*NB*NO)
#define OFF_PART_Z (OFF_PART_M + NC*LNCH*NB)
#define OFF_OUTBUF (OFF_PART_Z + NC*LNCH*NB)

template<int MODE>
__global__ __launch_bounds__(256)
void pass_k(const float* __restrict__ x, const float* __restrict__ W,
            const float* __restrict__ out_prev, float* __restrict__ logits,
            float* __restrict__ part_s, float* __restrict__ part_M, float* __restrict__ part_Z)
{
    const int ch = blockIdx.x;
    const int c  = blockIdx.y;
    const int r0 = ch * RB;
    const int t  = threadIdx.x;
    __shared__ __align__(16) float wlds[RB * 640];
    __shared__ __align__(16) float xlds[BT * 324];
    __shared__ float olds[BT * NO];
    {
        const float4* wg = (const float4*)(W + ((size_t)c * NR + r0) * (NI * NO));
        #pragma unroll
        for (int qq = t; qq < RB * NI * NO / 4; qq += 256) {
            float4 v = wg[qq];
            int r = qq >> 7, rem = qq & 127, i = rem >> 3, o4 = (rem & 7) << 2;
            float* dst = &wlds[r * 640 + i];
            dst[(o4 + 0) * 20] = v.x; dst[(o4 + 1) * 20] = v.y;
            dst[(o4 + 2) * 20] = v.z; dst[(o4 + 3) * 20] = v.w;
        }
    }
    const int o  = t & 31;
    const int bq = t >> 5;
    for (int bt = 0; bt < NB / BT; ++bt) {
        const int b0 = bt * BT;
        __syncthreads();
        {
            int b_l = t >> 4, j0 = t & 15;
            const float4* xg = (const float4*)(x + (size_t)(b0 + b_l) * (NR * NI) + (size_t)r0 * NI);
            float* xdst = &xlds[b_l * 324];
            #pragma unroll
            for (int j = j0; j < RB * NI / 4; j += 16) {
                float4 v = xg[j];
                int r = j >> 2, i4 = (j & 3) << 2;
                *((float4*)&xdst[r * 20 + i4]) = v;
            }
        }
        if (MODE >= 1) {
            for (int qq = t; qq < BT * NO; qq += 256) {
                int b_l = qq >> 5, oo = qq & 31;
                olds[qq] = out_prev[((size_t)c * NB + b0 + b_l) * NO + oo];
            }
        }
        __syncthreads();
        float acc[2], Mr[2], Zr[2];
        #pragma unroll
        for (int bs = 0; bs < 2; ++bs) { acc[bs] = 0.f; Mr[bs] = -INFINITY; Zr[bs] = 0.f; }
        for (int r = 0; r < RB; ++r) {
            const float* wp = &wlds[r * 640 + o * 20];
            float4 w0 = *(const float4*)(wp + 0);
            float4 w1 = *(const float4*)(wp + 4);
            float4 w2 = *(const float4*)(wp + 8);
            float4 w3 = *(const float4*)(wp + 12);
            #pragma unroll
            for (int bs = 0; bs < 2; ++bs) {
                int b_l = bq + bs * 8;
                const float* xp = &xlds[b_l * 324 + r * 20];
                float4 x0 = *(const float4*)(xp + 0);
                float4 x1 = *(const float4*)(xp + 4);
                float4 x2 = *(const float4*)(xp + 8);
                float4 x3 = *(const float4*)(xp + 12);
                float pv = x0.x*w0.x + x0.y*w0.y + x0.z*w0.z + x0.w*w0.w
                        + x1.x*w1.x + x1.y*w1.y + x1.z*w1.z + x1.w*w1.w
                        + x2.x*w2.x + x2.y*w2.y + x2.z*w2.z + x2.w*w2.w
                        + x3.x*w3.x + x3.y*w3.y + x3.z*w3.z + x3.w*w3.w;
                if (MODE == 0) {
                    acc[bs] += pv;
                } else {
                    float qv = pv * olds[b_l * NO + o];
                    qv += __shfl_xor(qv, 1);
                    qv += __shfl_xor(qv, 2);
                    qv += __shfl_xor(qv, 4);
                    qv += __shfl_xor(qv, 8);
                    qv += __shfl_xor(qv, 16);
                    float lval = qv;
                    size_t lidx = ((size_t)c * NB + b0 + b_l) * NR + r0 + r;
                    if (MODE == 2) lval += logits[lidx];
                    if (MODE == 1) { if (o == 0) logits[lidx] = lval; }
                    float Mn  = fmaxf(Mr[bs], lval);
                    float sc  = __expf(Mr[bs] - Mn);
                    float wg_ = __expf(lval - Mn);
                    Zr[bs]  = Zr[bs] * sc + wg_;
                    acc[bs] = acc[bs] * sc + wg_ * pv;
                    Mr[bs]  = Mn;
                }
            }
        }
        #pragma unroll
        for (int bs = 0; bs < 2; ++bs) {
            int b_l = bq + bs * 8;
            size_t pb = ((size_t)(c * LNCH + ch) * NB + b0 + b_l);
            part_s[pb * NO + o] = acc[bs];
            if (MODE >= 1 && o == 0) { part_M[pb] = Mr[bs]; part_Z[pb] = Zr[bs]; }
        }
    }
}

template<int UNIFORM>
__global__ __launch_bounds__(256)
void reduce_squash_k(const float* __restrict__ part_s, const float* __restrict__ part_M,
                     const float* __restrict__ part_Z, float* __restrict__ outp)
{
    const int c = blockIdx.x;
    const int t = threadIdx.x;
    __shared__ float slds[NB * NO];
    __shared__ float elds[LNCH * NB];
    __shared__ float rz[NB];
    __shared__ float red[8][NO];
    __shared__ float fo[NO];
    if (!UNIFORM) {
        if (t < NB) {
            float m = -INFINITY;
            for (int ch = 0; ch < LNCH; ++ch)
                m = fmaxf(m, part_M[(size_t)(c * LNCH + ch) * NB + t]);
            float z = 0.f;
            for (int ch = 0; ch < LNCH; ++ch) {
                float e = __expf(part_M[(size_t)(c * LNCH + ch) * NB + t] - m);
                elds[ch * NB + t] = e;
                z += part_Z[(size_t)(c * LNCH + ch) * NB + t] * e;
            }
            rz[t] = 1.f / z;
        }
        __syncthreads();
    }
    const int o = t & 31, bq = t >> 5;
    for (int k = 0; k < 16; ++k) {
        int b = bq + 8 * k;
        float s = 0.f;
        for (int ch = 0; ch < LNCH; ++ch) {
            float v = part_s[((size_t)(c * LNCH + ch) * NB + b) * NO + o];
            s += UNIFORM ? v : v * elds[ch * NB + b];
        }
        s = UNIFORM ? (s * (1.0f / NR)) : (s * rz[b]);
        slds[b * NO + o] = s;
    }
    __syncthreads();
    float pn = 0.f;
    for (int k = 0; k < 16; ++k) { int b = bq + 8 * k; float v = slds[b * NO + o]; pn += v * v; }
    red[bq][o] = pn;
    __syncthreads();
    if (t < NO) {
        float n2 = 0.f;
        for (int j = 0; j < 8; ++j) n2 += red[j][t];
        fo[t] = sqrtf(n2) / (1.f + n2);
    }
    __syncthreads();
    for (int k = 0; k < 16; ++k) {
        int b = bq + 8 * k;
        outp[((size_t)c * NB + b) * NO + o] = slds[b * NO + o] * fo[o];
    }
}

// ------------------------------------------------------------------
extern "C" void kernel_launch(void* const* d_in, const int* in_sizes, int n_in,
                              void* d_out, int out_size, void* d_ws, size_t ws_size,
                              hipStream_t stream)
{
    (void)in_sizes; (void)n_in; (void)out_size;
    const float* x = (const float*)d_in[0];
    const float* W = (const float*)d_in[1];
    float* wsf  = (float*)d_ws;
    float* outf = (float*)d_out;

    // new-path ws offsets (float units)
    const size_t SZ_WTS  = (size_t)NC * NR * 2 * 32 * 8;     // 5,898,240 u32
    const size_t SZ_XTS  = (size_t)2 * NR * NB * 8;          // 2,359,296 u32
    const size_t SZ_PART = (size_t)NC * NCHK * NB * 32;      // 1,966,080 f32
    const size_t SZ_PZ   = (size_t)NC * NCHK * NB;           //    61,440 f32
    const size_t OFF_XTS  = SZ_WTS;
    const size_t OFF_PART = OFF_XTS + SZ_XTS;
    const size_t OFF_PZ   = OFF_PART + SZ_PART;
    const size_t OFF_OACC = OFF_PZ + SZ_PZ;
    const size_t NEED = (OFF_OACC + (size_t)NC * NB * 32) * 4;

    if (ws_size >= NEED) {
        unsigned* wts = (unsigned*)d_ws;
        unsigned* xts = (unsigned*)d_ws + OFF_XTS;
        float* part_s = wsf + OFF_PART;
        float* pZ     = wsf + OFF_PZ;
        float* oacc   = wsf + OFF_OACC;

        convw_k<<<(NC*NR*NO + 255)/256, 256, 0, stream>>>(W, wts);
        convx_k<<<(NR*NB + 255)/256, 256, 0, stream>>>(x, xts);

        dim3 mg(NC, 4);
        // iter 0: uniform
        pass_f<0><<<960, 256, 0, stream>>>(xts, wts, nullptr, part_s, pZ);
        msq_k<0><<<mg, 256, 0, stream>>>(part_s, pZ, oacc, nullptr);
        // iter 1: softmax(pred . out0)
        pass_f<1><<<960, 256, 0, stream>>>(xts, wts, oacc, part_s, pZ);
        msq_k<1><<<mg, 256, 0, stream>>>(part_s, pZ, oacc, nullptr);
        // iter 2: softmax(pred . (out0+out1)) -> d_out
        pass_f<1><<<960, 256, 0, stream>>>(xts, wts, oacc, part_s, pZ);
        msq_k<2><<<mg, 256, 0, stream>>>(part_s, pZ, oacc, outf);
    } else {
        float* logits = wsf + OFF_LOGITS;
        float* part_s = wsf + OFF_PART_S;
        float* part_M = wsf + OFF_PART_M;
        float* part_Z = wsf + OFF_PART_Z;
        float* outbuf = wsf + OFF_OUTBUF;
        dim3 g(LNCH, NC), blk(256);
        pass_k<0><<<g, blk, 0, stream>>>(x, W, nullptr, nullptr, part_s, part_M, part_Z);
        reduce_squash_k<1><<<NC, blk, 0, stream>>>(part_s, part_M, part_Z, outbuf);
        pass_k<1><<<g, blk, 0, stream>>>(x, W, outbuf, logits, part_s, part_M, part_Z);
        reduce_squash_k<0><<<NC, blk, 0, stream>>>(part_s, part_M, part_Z, outbuf);
        pass_k<2><<<g, blk, 0, stream>>>(x, W, outbuf, logits, part_s, part_M, part_Z);
        reduce_squash_k<0><<<NC, blk, 0, stream>>>(part_s, part_M, part_Z, outf);
    }
}

// Round 4
// 74.728 us; speedup vs baseline: 9.2614x; 1.4278x over previous
//
#include <hip/hip_runtime.h>
#include <math.h>

// Problem constants
#define NB 128     // batch
#define NR 1152    // routes
#define NI 16      // in_ch
#define NO 32      // out_ch
#define NC 10      // capsules
#define NCHK 24    // partial chunks per capsule (route-chunks of 48)

typedef __attribute__((ext_vector_type(8))) short bf16x8;
typedef __attribute__((ext_vector_type(4))) float f32x4;
typedef __attribute__((ext_vector_type(16))) float f32x16;

__device__ __forceinline__ unsigned pk_bf16(float a, float b) {
    unsigned r;
    asm("v_cvt_pk_bf16_f32 %0, %1, %2" : "=v"(r) : "v"(a), "v"(b));
    return r;
}

// ------------------------------------------------------------------
// conv_k: fused W and x bf16x2-plane conversion.
// W path (blocks [0,1440)): W[c][r][i][o] f32 -> wts[((cr*2+pl)*32+o)*8 + half*4 + j]
//   row = 16 i-consecutive bf16 (8 u32) per (o, plane).
// x path (blocks [1440,2016)): x[b][r][i] f32 -> xts[((r*2+pl)*128+b)*8 + half*4 + j]
// ------------------------------------------------------------------
__global__ __launch_bounds__(256) void conv_k(const float* __restrict__ W,
                                              const float* __restrict__ x,
                                              unsigned* __restrict__ wts,
                                              unsigned* __restrict__ xts) {
    int bid = blockIdx.x;
    if (bid < 1440) {
        int tid = bid * 256 + threadIdx.x;      // (c*NR+r)*32 + o
        int o = tid & 31;
        size_t cr = (size_t)(tid >> 5);
        const float* src = W + cr * (NI * NO) + o;
        float w[16], hf[16];
        unsigned hu[8], lu[8];
#pragma unroll
        for (int i = 0; i < 16; ++i) w[i] = src[(size_t)i * 32];
#pragma unroll
        for (int j = 0; j < 8; ++j) hu[j] = pk_bf16(w[2*j], w[2*j+1]);
#pragma unroll
        for (int j = 0; j < 8; ++j) {
            hf[2*j]   = __uint_as_float(hu[j] << 16);
            hf[2*j+1] = __uint_as_float(hu[j] & 0xffff0000u);
        }
#pragma unroll
        for (int j = 0; j < 8; ++j) lu[j] = pk_bf16(w[2*j] - hf[2*j], w[2*j+1] - hf[2*j+1]);
        unsigned* dh = wts + ((cr*2 + 0)*32 + o)*8;
        unsigned* dl = wts + ((cr*2 + 1)*32 + o)*8;
        ((uint4*)dh)[0] = make_uint4(hu[0], hu[1], hu[2], hu[3]);
        ((uint4*)dh)[1] = make_uint4(hu[4], hu[5], hu[6], hu[7]);
        ((uint4*)dl)[0] = make_uint4(lu[0], lu[1], lu[2], lu[3]);
        ((uint4*)dl)[1] = make_uint4(lu[4], lu[5], lu[6], lu[7]);
    } else {
        int tid = (bid - 1440) * 256 + threadIdx.x;   // r*128 + b
        int r = tid >> 7, b = tid & 127;
        const float4* src = (const float4*)(x + ((size_t)b * NR + r) * 16);
        float4 a0 = src[0], a1 = src[1], a2 = src[2], a3 = src[3];
        float v[16] = {a0.x,a0.y,a0.z,a0.w, a1.x,a1.y,a1.z,a1.w,
                       a2.x,a2.y,a2.z,a2.w, a3.x,a3.y,a3.z,a3.w};
        unsigned hu[8], lu[8];
#pragma unroll
        for (int j = 0; j < 8; ++j) hu[j] = pk_bf16(v[2*j], v[2*j+1]);
#pragma unroll
        for (int j = 0; j < 8; ++j) {
            float h0 = __uint_as_float(hu[j] << 16);
            float h1 = __uint_as_float(hu[j] & 0xffff0000u);
            lu[j] = pk_bf16(v[2*j] - h0, v[2*j+1] - h1);
        }
        uint4* dh = (uint4*)(xts + ((size_t)r * 256 + b) * 8);
        dh[0] = make_uint4(hu[0], hu[1], hu[2], hu[3]);
        dh[1] = make_uint4(hu[4], hu[5], hu[6], hu[7]);
        uint4* dl = (uint4*)(xts + ((size_t)r * 256 + 128 + b) * 8);
        dl[0] = make_uint4(lu[0], lu[1], lu[2], lu[3]);
        dl[1] = make_uint4(lu[4], lu[5], lu[6], lu[7]);
    }
}

// ------------------------------------------------------------------
// pass_f: fused pred-recompute + (uniform | softmax-weighted) r-reduction.
// 240 blocks (c x 24 route-chunks of 48), XCD-chunked. 512 thr = 8 waves:
// wave = (h = route-quarter of 12, p = batch-half of 64). 32x32x16 MFMA:
// A = W (M=o), B = x (N=b). C: col(l&31)=b, row(reg&3)+8*(reg>>2)+4*(l>>5)=o.
// 3 plane-MFMAs per (route, 32-batch): Wh.xh + Wl.xh + Wh.xl.
// MODE 0: acc += pred. MODE 1: d = pred.oacc, e=exp(d-20), Z+=e, acc+=e*pred.
// 8-wave LDS merge (XOR-swizzled) -> part_s[c][rch][128][32], pZ[c][rch][128].
// ------------------------------------------------------------------
template<int MODE>
__global__ __launch_bounds__(512) void pass_f(const unsigned* __restrict__ xts,
                                              const unsigned* __restrict__ wts,
                                              const float* __restrict__ oacc,
                                              float* __restrict__ part_s,
                                              float* __restrict__ pZ)
{
    __shared__ float lds[16384];   // 64 KB: oacc stage (16.5 KB) then 4-way merge
    int pb = blockIdx.x;
    int lin = (pb & 7) * 30 + (pb >> 3);   // chunked XCD swizzle (240 = 8*30)
    int rch = lin / 10;
    int c   = lin - rch * 10;
    const int t = threadIdx.x;
    const int w = t >> 6, l = t & 63;
    const int h = w >> 1, bp = w & 1;
    const int lo5 = l & 31, hi1 = l >> 5;
    const int r0 = rch * 48 + h * 12;

    if (MODE == 1) {
        const float* ob = oacc + (size_t)c * NB * 32;
        for (int idx = t; idx < 4096; idx += 512)
            lds[(idx >> 5) * 33 + (idx & 31)] = ob[idx];
    }
    __syncthreads();

    float ov0[16], ov1[16], acc0[16], acc1[16];
#pragma unroll
    for (int j = 0; j < 16; ++j) { acc0[j] = 0.f; acc1[j] = 0.f; }
    if (MODE == 1) {
#pragma unroll
        for (int j = 0; j < 16; ++j) {
            int orow = (j & 3) + 8 * (j >> 2) + 4 * hi1;
            ov0[j] = lds[(bp * 64 + lo5) * 33 + orow];
            ov1[j] = lds[(bp * 64 + 32 + lo5) * 33 + orow];
        }
    }
    float Z0 = 0.f, Z1 = 0.f;
    f32x16 zz;
#pragma unroll
    for (int j = 0; j < 16; ++j) zz[j] = 0.f;

    const unsigned* wbase = wts + ((size_t)(c * NR + r0) * 2) * 256 + lo5 * 8 + hi1 * 4;
    const unsigned* xbase = xts + (size_t)r0 * 2048 + bp * 512 + lo5 * 8 + hi1 * 4;

    for (int rr = 0; rr < 12; ++rr) {
        union { uint4 u; bf16x8 v; } Ah, Al, Bh0, Bh1, Bl0, Bl1;
        Ah.u  = *(const uint4*)(wbase + (size_t)rr * 512);
        Al.u  = *(const uint4*)(wbase + (size_t)rr * 512 + 256);
        Bh0.u = *(const uint4*)(xbase + (size_t)rr * 2048);
        Bh1.u = *(const uint4*)(xbase + (size_t)rr * 2048 + 256);
        Bl0.u = *(const uint4*)(xbase + (size_t)rr * 2048 + 1024);
        Bl1.u = *(const uint4*)(xbase + (size_t)rr * 2048 + 1280);
        f32x16 q0, q1;
        q0 = __builtin_amdgcn_mfma_f32_32x32x16_bf16(Ah.v, Bh0.v, zz, 0, 0, 0);
        q1 = __builtin_amdgcn_mfma_f32_32x32x16_bf16(Ah.v, Bh1.v, zz, 0, 0, 0);
        q0 = __builtin_amdgcn_mfma_f32_32x32x16_bf16(Al.v, Bh0.v, q0, 0, 0, 0);
        q1 = __builtin_amdgcn_mfma_f32_32x32x16_bf16(Al.v, Bh1.v, q1, 0, 0, 0);
        q0 = __builtin_amdgcn_mfma_f32_32x32x16_bf16(Ah.v, Bl0.v, q0, 0, 0, 0);
        q1 = __builtin_amdgcn_mfma_f32_32x32x16_bf16(Ah.v, Bl1.v, q1, 0, 0, 0);
        if (MODE == 0) {
#pragma unroll
            for (int j = 0; j < 16; ++j) { acc0[j] += q0[j]; acc1[j] += q1[j]; }
        } else {
            float d0 = 0.f, d1 = 0.f;
#pragma unroll
            for (int j = 0; j < 16; ++j) {
                d0 = fmaf(q0[j], ov0[j], d0);
                d1 = fmaf(q1[j], ov1[j], d1);
            }
            d0 += __shfl_xor(d0, 32);
            d1 += __shfl_xor(d1, 32);
            float e0 = __expf(d0 - 20.0f);
            float e1 = __expf(d1 - 20.0f);
            Z0 += e0; Z1 += e1;
#pragma unroll
            for (int j = 0; j < 16; ++j) {
                acc0[j] = fmaf(e0, q0[j], acc0[j]);
                acc1[j] = fmaf(e1, q1[j], acc1[j]);
            }
        }
    }

    // ---- 8-wave LDS merge (4 h-slices; b-halves disjoint) ----
    const int b0 = bp * 64 + lo5, b1 = b0 + 32;
    __syncthreads();
#pragma unroll
    for (int j = 0; j < 16; ++j) {
        int orow = (j & 3) + 8 * (j >> 2) + 4 * hi1;
        lds[h * 4096 + b0 * 32 + (orow ^ lo5)] = acc0[j];
        lds[h * 4096 + b1 * 32 + (orow ^ lo5)] = acc1[j];
    }
    __syncthreads();
    float* po = part_s + (size_t)(c * NCHK + rch) * 4096;
    for (int idx = t; idx < 4096; idx += 512) {
        int b = idx >> 5, o = idx & 31;
        float s = 0.f;
#pragma unroll
        for (int hh = 0; hh < 4; ++hh)
            s += lds[hh * 4096 + b * 32 + (o ^ (b & 31))];
        po[idx] = s;
    }
    if (MODE == 1) {
        __syncthreads();
        if (l < 32) {
            lds[h * 128 + bp * 64 + lo5] = Z0;
            lds[h * 128 + bp * 64 + 32 + lo5] = Z1;
        }
        __syncthreads();
        if (t < 128) {
            float z = lds[t] + lds[128 + t] + lds[256 + t] + lds[384 + t];
            pZ[(size_t)(c * NCHK + rch) * 128 + t] = z;
        }
    }
}

// ------------------------------------------------------------------
// msq: merge chunk partials -> s, squash over batch, update oacc / out.
// MODE 0: uniform (s = sum/1152), oacc = squash. 1: oacc += squash. 2: out.
// Grid (10 c, 4 o-groups), 256 thr: t = o_off(8) x b_lo(32)
// ------------------------------------------------------------------
template<int MODE>
__global__ __launch_bounds__(256) void msq_k(const float* __restrict__ part_s,
                                             const float* __restrict__ pZ,
                                             float* __restrict__ oacc,
                                             float* __restrict__ dout)
{
    const int c = blockIdx.x, og = blockIdx.y;
    const int t = threadIdx.x;
    const int o_off = t & 7, b_lo = t >> 3;
    const int o = og * 8 + o_off;

    float sv[4];
    float pn = 0.f;
#pragma unroll
    for (int k = 0; k < 4; ++k) {
        int bb = b_lo + 32 * k;
        float s = 0.f;
#pragma unroll
        for (int ch = 0; ch < NCHK; ++ch)
            s += part_s[(((size_t)c * NCHK + ch) * NB + bb) * 32 + o];
        if (MODE == 0) {
            sv[k] = s * (1.0f / 1152.0f);
        } else {
            float z = 0.f;
#pragma unroll
            for (int ch = 0; ch < NCHK; ++ch)
                z += pZ[((size_t)c * NCHK + ch) * NB + bb];
            sv[k] = s / z;
        }
        pn = fmaf(sv[k], sv[k], pn);
    }
    __shared__ float red[256];
    __shared__ float fsh[8];
    red[t] = pn;
    __syncthreads();
    if (t < 8) {
        float n2 = 0.f;
#pragma unroll
        for (int j = 0; j < 32; ++j) n2 += red[t + 8 * j];
        fsh[t] = sqrtf(n2) / (1.0f + n2);
    }
    __syncthreads();
    float f = fsh[o_off];
#pragma unroll
    for (int k = 0; k < 4; ++k) {
        int bb = b_lo + 32 * k;
        float v = sv[k] * f;
        size_t idx = ((size_t)c * NB + bb) * 32 + o;
        if (MODE == 0) oacc[idx] = v;
        if (MODE == 1) oacc[idx] += v;
        if (MODE == 2) dout[idx] = v;
    }
}

// ------------------------------------------------------------------
// LEGACY FALLBACK (round-1 kernels, used only if ws_size is small)
// ------------------------------------------------------------------
#define RB 16
#define LNCH (NR / RB)
#define BT 16
#define OFF_LOGITS 0
#define OFF_PART_S (OFF_LOGITS + NC*NB*NR)
#define OFF_PART_M (OFF_PART_S + NC*LNCH*NB*NO)
#define OFF_PART_Z (OFF_PART_M + NC*LNCH*NB)
#define OFF_OUTBUF (OFF_PART_Z + NC*LNCH*NB)

template<int MODE>
__global__ __launch_bounds__(256)
void pass_k(const float* __restrict__ x, const float* __restrict__ W,
            const float* __restrict__ out_prev, float* __restrict__ logits,
            float* __restrict__ part_s, float* __restrict__ part_M, float* __restrict__ part_Z)
{
    const int ch = blockIdx.x;
    const int c  = blockIdx.y;
    const int r0 = ch * RB;
    const int t  = threadIdx.x;
    __shared__ __align__(16) float wlds[RB * 640];
    __shared__ __align__(16) float xlds[BT * 324];
    __shared__ float olds[BT * NO];
    {
        const float4* wg = (const float4*)(W + ((size_t)c * NR + r0) * (NI * NO));
        #pragma unroll
        for (int qq = t; qq < RB * NI * NO / 4; qq += 256) {
            float4 v = wg[qq];
            int r = qq >> 7, rem = qq & 127, i = rem >> 3, o4 = (rem & 7) << 2;
            float* dst = &wlds[r * 640 + i];
            dst[(o4 + 0) * 20] = v.x; dst[(o4 + 1) * 20] = v.y;
            dst[(o4 + 2) * 20] = v.z; dst[(o4 + 3) * 20] = v.w;
        }
    }
    const int o  = t & 31;
    const int bq = t >> 5;
    for (int bt = 0; bt < NB / BT; ++bt) {
        const int b0 = bt * BT;
        __syncthreads();
        {
            int b_l = t >> 4, j0 = t & 15;
            const float4* xg = (const float4*)(x + (size_t)(b0 + b_l) * (NR * NI) + (size_t)r0 * NI);
            float* xdst = &xlds[b_l * 324];
            #pragma unroll
            for (int j = j0; j < RB * NI / 4; j += 16) {
                float4 v = xg[j];
                int r = j >> 2, i4 = (j & 3) << 2;
                *((float4*)&xdst[r * 20 + i4]) = v;
            }
        }
        if (MODE >= 1) {
            for (int qq = t; qq < BT * NO; qq += 256) {
                int b_l = qq >> 5, oo = qq & 31;
                olds[qq] = out_prev[((size_t)c * NB + b0 + b_l) * NO + oo];
            }
        }
        __syncthreads();
        float acc[2], Mr[2], Zr[2];
        #pragma unroll
        for (int bs = 0; bs < 2; ++bs) { acc[bs] = 0.f; Mr[bs] = -INFINITY; Zr[bs] = 0.f; }
        for (int r = 0; r < RB; ++r) {
            const float* wp = &wlds[r * 640 + o * 20];
            float4 w0 = *(const float4*)(wp + 0);
            float4 w1 = *(const float4*)(wp + 4);
            float4 w2 = *(const float4*)(wp + 8);
            float4 w3 = *(const float4*)(wp + 12);
            #pragma unroll
            for (int bs = 0; bs < 2; ++bs) {
                int b_l = bq + bs * 8;
                const float* xp = &xlds[b_l * 324 + r * 20];
                float4 x0 = *(const float4*)(xp + 0);
                float4 x1 = *(const float4*)(xp + 4);
                float4 x2 = *(const float4*)(xp + 8);
                float4 x3 = *(const float4*)(xp + 12);
                float pv = x0.x*w0.x + x0.y*w0.y + x0.z*w0.z + x0.w*w0.w
                        + x1.x*w1.x + x1.y*w1.y + x1.z*w1.z + x1.w*w1.w
                        + x2.x*w2.x + x2.y*w2.y + x2.z*w2.z + x2.w*w2.w
                        + x3.x*w3.x + x3.y*w3.y + x3.z*w3.z + x3.w*w3.w;
                if (MODE == 0) {
                    acc[bs] += pv;
                } else {
                    float qv = pv * olds[b_l * NO + o];
                    qv += __shfl_xor(qv, 1);
                    qv += __shfl_xor(qv, 2);
                    qv += __shfl_xor(qv, 4);
                    qv += __shfl_xor(qv, 8);
                    qv += __shfl_xor(qv, 16);
                    float lval = qv;
                    size_t lidx = ((size_t)c * NB + b0 + b_l) * NR + r0 + r;
                    if (MODE == 2) lval += logits[lidx];
                    if (MODE == 1) { if (o == 0) logits[lidx] = lval; }
                    float Mn  = fmaxf(Mr[bs], lval);
                    float sc  = __expf(Mr[bs] - Mn);
                    float wg_ = __expf(lval - Mn);
                    Zr[bs]  = Zr[bs] * sc + wg_;
                    acc[bs] = acc[bs] * sc + wg_ * pv;
                    Mr[bs]  = Mn;
                }
            }
        }
        #pragma unroll
        for (int bs = 0; bs < 2; ++bs) {
            int b_l = bq + bs * 8;
            size_t pb2 = ((size_t)(c * LNCH + ch) * NB + b0 + b_l);
            part_s[pb2 * NO + o] = acc[bs];
            if (MODE >= 1 && o == 0) { part_M[pb2] = Mr[bs]; part_Z[pb2] = Zr[bs]; }
        }
    }
}

template<int UNIFORM>
__global__ __launch_bounds__(256)
void reduce_squash_k(const float* __restrict__ part_s, const float* __restrict__ part_M,
                     const float* __restrict__ part_Z, float* __restrict__ outp)
{
    const int c = blockIdx.x;
    const int t = threadIdx.x;
    __shared__ float slds[NB * NO];
    __shared__ float elds[LNCH * NB];
    __shared__ float rz[NB];
    __shared__ float red[8][NO];
    __shared__ float fo[NO];
    if (!UNIFORM) {
        if (t < NB) {
            float m = -INFINITY;
            for (int ch = 0; ch < LNCH; ++ch)
                m = fmaxf(m, part_M[(size_t)(c * LNCH + ch) * NB + t]);
            float z = 0.f;
            for (int ch = 0; ch < LNCH; ++ch) {
                float e = __expf(part_M[(size_t)(c * LNCH + ch) * NB + t] - m);
                elds[ch * NB + t] = e;
                z += part_Z[(size_t)(c * LNCH + ch) * NB + t] * e;
            }
            rz[t] = 1.f / z;
        }
        __syncthreads();
    }
    const int o = t & 31, bq = t >> 5;
    for (int k = 0; k < 16; ++k) {
        int b = bq + 8 * k;
        float s = 0.f;
        for (int ch = 0; ch < LNCH; ++ch) {
            float v = part_s[((size_t)(c * LNCH + ch) * NB + b) * NO + o];
            s += UNIFORM ? v : v * elds[ch * NB + b];
        }
        s = UNIFORM ? (s * (1.0f / NR)) : (s * rz[b]);
        slds[b * NO + o] = s;
    }
    __syncthreads();
    float pn = 0.f;
    for (int k = 0; k < 16; ++k) { int b = bq + 8 * k; float v = slds[b * NO + o]; pn += v * v; }
    red[bq][o] = pn;
    __syncthreads();
    if (t < NO) {
        float n2 = 0.f;
        for (int j = 0; j < 8; ++j) n2 += red[j][t];
        fo[t] = sqrtf(n2) / (1.f + n2);
    }
    __syncthreads();
    for (int k = 0; k < 16; ++k) {
        int b = bq + 8 * k;
        outp[((size_t)c * NB + b) * NO + o] = slds[b * NO + o] * fo[o];
    }
}

// ------------------------------------------------------------------
extern "C" void kernel_launch(void* const* d_in, const int* in_sizes, int n_in,
                              void* d_out, int out_size, void* d_ws, size_t ws_size,
                              hipStream_t stream)
{
    (void)in_sizes; (void)n_in; (void)out_size;
    const float* x = (const float*)d_in[0];
    const float* W = (const float*)d_in[1];
    float* wsf  = (float*)d_ws;
    float* outf = (float*)d_out;

    // ws offsets (float/u32 units)
    const size_t SZ_WTS  = (size_t)NC * NR * 2 * 32 * 8;     // 5,898,240
    const size_t SZ_XTS  = (size_t)NR * 2 * 128 * 8;         // 2,359,296
    const size_t SZ_PART = (size_t)NC * NCHK * NB * 32;      //   983,040
    const size_t SZ_PZ   = (size_t)NC * NCHK * NB;           //    30,720
    const size_t OFF_XTS  = SZ_WTS;
    const size_t OFF_PART = OFF_XTS + SZ_XTS;
    const size_t OFF_PZ   = OFF_PART + SZ_PART;
    const size_t OFF_OACC = OFF_PZ + SZ_PZ;
    const size_t NEED = (OFF_OACC + (size_t)NC * NB * 32) * 4;

    if (ws_size >= NEED) {
        unsigned* wts = (unsigned*)d_ws;
        unsigned* xts = (unsigned*)d_ws + OFF_XTS;
        float* part_s = wsf + OFF_PART;
        float* pZ     = wsf + OFF_PZ;
        float* oacc   = wsf + OFF_OACC;

        conv_k<<<2016, 256, 0, stream>>>(W, x, wts, xts);

        dim3 mg(NC, 4);
        pass_f<0><<<240, 512, 0, stream>>>(xts, wts, nullptr, part_s, pZ);
        msq_k<0><<<mg, 256, 0, stream>>>(part_s, pZ, oacc, nullptr);
        pass_f<1><<<240, 512, 0, stream>>>(xts, wts, oacc, part_s, pZ);
        msq_k<1><<<mg, 256, 0, stream>>>(part_s, pZ, oacc, nullptr);
        pass_f<1><<<240, 512, 0, stream>>>(xts, wts, oacc, part_s, pZ);
        msq_k<2><<<mg, 256, 0, stream>>>(part_s, pZ, oacc, outf);
    } else {
        float* logits = wsf + OFF_LOGITS;
        float* part_s = wsf + OFF_PART_S;
        float* part_M = wsf + OFF_PART_M;
        float* part_Z = wsf + OFF_PART_Z;
        float* outbuf = wsf + OFF_OUTBUF;
        dim3 g(LNCH, NC), blk(256);
        pass_k<0><<<g, blk, 0, stream>>>(x, W, nullptr, nullptr, part_s, part_M, part_Z);
        reduce_squash_k<1><<<NC, blk, 0, stream>>>(part_s, part_M, part_Z, outbuf);
        pass_k<1><<<g, blk, 0, stream>>>(x, W, outbuf, logits, part_s, part_M, part_Z);
        reduce_squash_k<0><<<NC, blk, 0, stream>>>(part_s, part_M, part_Z, outbuf);
        pass_k<2><<<g, blk, 0, stream>>>(x, W, outbuf, logits, part_s, part_M, part_Z);
        reduce_squash_k<0><<<NC, blk, 0, stream>>>(part_s, part_M, part_Z, outf);
    }
}

// Round 5
// 73.351 us; speedup vs baseline: 9.4351x; 1.0188x over previous
//
#include <hip/hip_runtime.h>
#include <math.h>

// Problem constants
#define NB 128     // batch
#define NR 1152    // routes
#define NC 10      // capsules
#define NCHK 24    // partial chunks per capsule (route-chunks of 48)

typedef __attribute__((ext_vector_type(8))) short bf16x8;
typedef __attribute__((ext_vector_type(16))) float f32x16;

__device__ __forceinline__ unsigned pk_bf16(float a, float b) {
    unsigned r;
    asm("v_cvt_pk_bf16_f32 %0, %1, %2" : "=v"(r) : "v"(a), "v"(b));
    return r;
}

// ------------------------------------------------------------------
// pass_g: fused on-the-fly bf16x3 conversion + pred-recompute +
// (uniform | softmax-weighted) route reduction. No precomputed operands.
// 240 blocks (c x 24 route-chunks of 48), XCD-chunked (all 10 c of an rch
// land on one XCD -> x slice L2-reused across capsules). 512 thr = 8 waves:
// wave = (h = route-quarter of 12, bp = batch-half of 64).
// 32x32x16 MFMA: A = W (M=o), B = x (N=b). C: col(l&31)=b,
// row(reg&3)+8*(reg>>2)+4*(l>>5)=o. 3 plane-MFMAs per (route, 32-batch):
// Wh.xh + Wl.xh + Wh.xl (fp32-accurate to ~2^-17).
// MODE 0: acc chained through MFMA C operand (uniform sum).
// MODE 1: d = pred.oacc, e = exp(d-20), Z += e, acc += e*pred.
// 8-wave LDS merge (XOR-swizzled) -> part_s[c][rch][128][32], pZ[c][rch][128].
// ------------------------------------------------------------------
template<int MODE>
__global__ __launch_bounds__(512, 2) void pass_g(const float* __restrict__ x,
                                                 const float* __restrict__ W,
                                                 const float* __restrict__ oacc,
                                                 float* __restrict__ part_s,
                                                 float* __restrict__ pZ)
{
    __shared__ float lds[16384];   // 64 KB: oacc stage (16.5 KB) then 4-way merge
    const int pb = blockIdx.x;
    const int lin = (pb & 7) * 30 + (pb >> 3);   // chunked XCD swizzle (240 = 8*30)
    const int rch = lin / 10;
    const int c   = lin - rch * 10;
    const int t = threadIdx.x;
    const int w = t >> 6, l = t & 63;
    const int h = w >> 1, bp = w & 1;
    const int lo5 = l & 31, hi1 = l >> 5;
    const int r0 = rch * 48 + h * 12;

    if (MODE == 1) {
        const float* ob = oacc + (size_t)c * NB * 32;
        for (int idx = t; idx < 4096; idx += 512)
            lds[(idx >> 5) * 33 + (idx & 31)] = ob[idx];
    }
    __syncthreads();

    float ov0[16], ov1[16];
    if (MODE == 1) {
#pragma unroll
        for (int j = 0; j < 16; ++j) {
            int orow = (j & 3) + 8 * (j >> 2) + 4 * hi1;
            ov0[j] = lds[(bp * 64 + lo5) * 33 + orow];
            ov1[j] = lds[(bp * 64 + 32 + lo5) * 33 + orow];
        }
    }

    f32x16 acc0, acc1, zz;
#pragma unroll
    for (int j = 0; j < 16; ++j) { acc0[j] = 0.f; acc1[j] = 0.f; zz[j] = 0.f; }
    float Z0 = 0.f, Z1 = 0.f;

    // W element (r, i=hi1*8+j, o=lo5): wb + (r-r0)*512 + j*32
    const float* wb  = W + ((size_t)(c * NR + r0) * 16 + hi1 * 8) * 32 + lo5;
    // x row for (b, r): 8 consecutive f32 starting at i=hi1*8
    const float* xp0 = x + ((size_t)(bp * 64 + lo5) * NR + r0) * 16 + hi1 * 8;
    const float* xp1 = x + ((size_t)(bp * 64 + 32 + lo5) * NR + r0) * 16 + hi1 * 8;

    for (int rr = 0; rr < 12; ++rr) {
        // ---- W fragment: 8 strided f32 -> hi/lo bf16 planes ----
        float wv[8];
#pragma unroll
        for (int j = 0; j < 8; ++j) wv[j] = wb[(size_t)rr * 512 + j * 32];
        union { unsigned u[4]; bf16x8 v; } Ah, Al, Xh0, Xl0, Xh1, Xl1;
#pragma unroll
        for (int j = 0; j < 4; ++j) Ah.u[j] = pk_bf16(wv[2*j], wv[2*j+1]);
#pragma unroll
        for (int j = 0; j < 4; ++j) {
            float g0 = __uint_as_float(Ah.u[j] << 16);
            float g1 = __uint_as_float(Ah.u[j] & 0xffff0000u);
            Al.u[j] = pk_bf16(wv[2*j] - g0, wv[2*j+1] - g1);
        }
        // ---- x fragments: 8 consecutive f32 per bgroup -> hi/lo planes ----
        float4 u0 = *(const float4*)(xp0 + rr * 16);
        float4 u1 = *(const float4*)(xp0 + rr * 16 + 4);
        float xv0[8] = {u0.x,u0.y,u0.z,u0.w, u1.x,u1.y,u1.z,u1.w};
#pragma unroll
        for (int j = 0; j < 4; ++j) Xh0.u[j] = pk_bf16(xv0[2*j], xv0[2*j+1]);
#pragma unroll
        for (int j = 0; j < 4; ++j) {
            float g0 = __uint_as_float(Xh0.u[j] << 16);
            float g1 = __uint_as_float(Xh0.u[j] & 0xffff0000u);
            Xl0.u[j] = pk_bf16(xv0[2*j] - g0, xv0[2*j+1] - g1);
        }
        float4 v0 = *(const float4*)(xp1 + rr * 16);
        float4 v1 = *(const float4*)(xp1 + rr * 16 + 4);
        float xv1[8] = {v0.x,v0.y,v0.z,v0.w, v1.x,v1.y,v1.z,v1.w};
#pragma unroll
        for (int j = 0; j < 4; ++j) Xh1.u[j] = pk_bf16(xv1[2*j], xv1[2*j+1]);
#pragma unroll
        for (int j = 0; j < 4; ++j) {
            float g0 = __uint_as_float(Xh1.u[j] << 16);
            float g1 = __uint_as_float(Xh1.u[j] & 0xffff0000u);
            Xl1.u[j] = pk_bf16(xv1[2*j] - g0, xv1[2*j+1] - g1);
        }

        if (MODE == 0) {
            acc0 = __builtin_amdgcn_mfma_f32_32x32x16_bf16(Ah.v, Xh0.v, acc0, 0, 0, 0);
            acc0 = __builtin_amdgcn_mfma_f32_32x32x16_bf16(Al.v, Xh0.v, acc0, 0, 0, 0);
            acc0 = __builtin_amdgcn_mfma_f32_32x32x16_bf16(Ah.v, Xl0.v, acc0, 0, 0, 0);
            acc1 = __builtin_amdgcn_mfma_f32_32x32x16_bf16(Ah.v, Xh1.v, acc1, 0, 0, 0);
            acc1 = __builtin_amdgcn_mfma_f32_32x32x16_bf16(Al.v, Xh1.v, acc1, 0, 0, 0);
            acc1 = __builtin_amdgcn_mfma_f32_32x32x16_bf16(Ah.v, Xl1.v, acc1, 0, 0, 0);
        } else {
            f32x16 q0, q1;
            q0 = __builtin_amdgcn_mfma_f32_32x32x16_bf16(Ah.v, Xh0.v, zz, 0, 0, 0);
            q1 = __builtin_amdgcn_mfma_f32_32x32x16_bf16(Ah.v, Xh1.v, zz, 0, 0, 0);
            q0 = __builtin_amdgcn_mfma_f32_32x32x16_bf16(Al.v, Xh0.v, q0, 0, 0, 0);
            q1 = __builtin_amdgcn_mfma_f32_32x32x16_bf16(Al.v, Xh1.v, q1, 0, 0, 0);
            q0 = __builtin_amdgcn_mfma_f32_32x32x16_bf16(Ah.v, Xl0.v, q0, 0, 0, 0);
            q1 = __builtin_amdgcn_mfma_f32_32x32x16_bf16(Ah.v, Xl1.v, q1, 0, 0, 0);
            float d0 = 0.f, d1 = 0.f;
#pragma unroll
            for (int j = 0; j < 16; ++j) {
                d0 = fmaf(q0[j], ov0[j], d0);
                d1 = fmaf(q1[j], ov1[j], d1);
            }
            d0 += __shfl_xor(d0, 32);
            d1 += __shfl_xor(d1, 32);
            float e0 = __expf(d0 - 20.0f);
            float e1 = __expf(d1 - 20.0f);
            Z0 += e0; Z1 += e1;
#pragma unroll
            for (int j = 0; j < 16; ++j) {
                acc0[j] = fmaf(e0, q0[j], acc0[j]);
                acc1[j] = fmaf(e1, q1[j], acc1[j]);
            }
        }
    }

    // ---- 8-wave LDS merge (4 h-slices; b-halves disjoint) ----
    const int b0 = bp * 64 + lo5, b1 = b0 + 32;
    __syncthreads();
#pragma unroll
    for (int j = 0; j < 16; ++j) {
        int orow = (j & 3) + 8 * (j >> 2) + 4 * hi1;
        lds[h * 4096 + b0 * 32 + (orow ^ lo5)] = acc0[j];
        lds[h * 4096 + b1 * 32 + (orow ^ lo5)] = acc1[j];
    }
    __syncthreads();
    float* po = part_s + (size_t)(c * NCHK + rch) * 4096;
    for (int idx = t; idx < 4096; idx += 512) {
        int b = idx >> 5, o = idx & 31;
        float s = 0.f;
#pragma unroll
        for (int hh = 0; hh < 4; ++hh)
            s += lds[hh * 4096 + b * 32 + (o ^ (b & 31))];
        po[idx] = s;
    }
    if (MODE == 1) {
        __syncthreads();
        if (l < 32) {
            lds[h * 128 + bp * 64 + lo5] = Z0;
            lds[h * 128 + bp * 64 + 32 + lo5] = Z1;
        }
        __syncthreads();
        if (t < 128) {
            float z = lds[t] + lds[128 + t] + lds[256 + t] + lds[384 + t];
            pZ[(size_t)(c * NCHK + rch) * 128 + t] = z;
        }
    }
}

// ------------------------------------------------------------------
// msq: merge chunk partials -> s, squash over batch, update oacc / out.
// MODE 0: uniform (s = sum/1152), oacc = squash. 1: oacc += squash. 2: out.
// Grid (10 c, 4 o-groups), 256 thr: t = o_off(8) x b_lo(32)
// ------------------------------------------------------------------
template<int MODE>
__global__ __launch_bounds__(256) void msq_k(const float* __restrict__ part_s,
                                             const float* __restrict__ pZ,
                                             float* __restrict__ oacc,
                                             float* __restrict__ dout)
{
    const int c = blockIdx.x, og = blockIdx.y;
    const int t = threadIdx.x;
    const int o_off = t & 7, b_lo = t >> 3;
    const int o = og * 8 + o_off;

    float sv[4];
    float pn = 0.f;
#pragma unroll
    for (int k = 0; k < 4; ++k) {
        int bb = b_lo + 32 * k;
        float s = 0.f;
#pragma unroll
        for (int ch = 0; ch < NCHK; ++ch)
            s += part_s[(((size_t)c * NCHK + ch) * NB + bb) * 32 + o];
        if (MODE == 0) {
            sv[k] = s * (1.0f / 1152.0f);
        } else {
            float z = 0.f;
#pragma unroll
            for (int ch = 0; ch < NCHK; ++ch)
                z += pZ[((size_t)c * NCHK + ch) * NB + bb];
            sv[k] = s / z;
        }
        pn = fmaf(sv[k], sv[k], pn);
    }
    __shared__ float red[256];
    __shared__ float fsh[8];
    red[t] = pn;
    __syncthreads();
    if (t < 8) {
        float n2 = 0.f;
#pragma unroll
        for (int j = 0; j < 32; ++j) n2 += red[t + 8 * j];
        fsh[t] = sqrtf(n2) / (1.0f + n2);   // (n2/(1+n2))/sqrt(n2)
    }
    __syncthreads();
    float f = fsh[o_off];
#pragma unroll
    for (int k = 0; k < 4; ++k) {
        int bb = b_lo + 32 * k;
        float v = sv[k] * f;
        size_t idx = ((size_t)c * NB + bb) * 32 + o;
        if (MODE == 0) oacc[idx] = v;
        if (MODE == 1) oacc[idx] += v;
        if (MODE == 2) dout[idx] = v;
    }
}

// ------------------------------------------------------------------
extern "C" void kernel_launch(void* const* d_in, const int* in_sizes, int n_in,
                              void* d_out, int out_size, void* d_ws, size_t ws_size,
                              hipStream_t stream)
{
    (void)in_sizes; (void)n_in; (void)out_size; (void)ws_size;
    const float* x = (const float*)d_in[0];
    const float* W = (const float*)d_in[1];
    float* wsf  = (float*)d_ws;
    float* outf = (float*)d_out;

    // ws layout (float units): part_s 983,040 | pZ 30,720 | oacc 40,960
    // total need = 4.2 MB  (harness ws has been >= 37 MB every round)
    float* part_s = wsf;
    float* pZ     = wsf + (size_t)NC * NCHK * NB * 32;
    float* oacc   = pZ  + (size_t)NC * NCHK * NB;

    dim3 mg(NC, 4);
    // iter 0: uniform weights
    pass_g<0><<<240, 512, 0, stream>>>(x, W, nullptr, part_s, pZ);
    msq_k<0><<<mg, 256, 0, stream>>>(part_s, pZ, oacc, nullptr);
    // iter 1: softmax(pred . out0)
    pass_g<1><<<240, 512, 0, stream>>>(x, W, oacc, part_s, pZ);
    msq_k<1><<<mg, 256, 0, stream>>>(part_s, pZ, oacc, nullptr);
    // iter 2: softmax(pred . (out0+out1)) -> d_out
    pass_g<1><<<240, 512, 0, stream>>>(x, W, oacc, part_s, pZ);
    msq_k<2><<<mg, 256, 0, stream>>>(part_s, pZ, oacc, outf);
}